// Round 3
// baseline (252.080 us; speedup 1.0000x reference)
//
#include <hip/hip_runtime.h>

// HistogramLoss: two [32,3,512,512] fp32 inputs, per-(B,C) 64-bin histogram
// over [0,1], row-normalized (row count exactly 2^18), L1 mean of diff.
//
// R8: concurrency fix. R7's "pipeline" collapsed: VGPR_Count=36 proves the
// allocator coalesced c/n regs and serialized loads (needs 34 regs for
// planes+4 floats alone). All of R5/R6/R7 sit at ~1 dword/cy/CU and the
// L3-warm replays run the SAME 86us -> not HBM-bound, not VALU-bound
// (35%): Little's-law bound (bytes in flight / loaded latency). Fix:
//  (1) ring-8 register prefetch, rotate-in-place: PROC4(fk); reload fk;
//      sched_barrier(0) after each stage makes sinking the reload
//      ILLEGAL (the mechanism R7 lacked). 8 float4 permanently in
//      flight per wave.
//  (2) BPR back to 8: 1536 blocks, 6 blocks/CU, 24 waves/CU ->
//      24 waves x 8KB = 192KB in flight per CU (was ~16KB).
//      128 elems/thread -> 8 planes (capacity 255, exact).
//  (3) __launch_bounds__(256,6): VGPR cap ~85, keeps 6 blocks resident.
// Predict: hist 86->35-50us, VALUBusy 60-85%, VGPR 64-84, occupancy ~70%.

#define HW        262144             // 512*512 = 2^18
#define ROWS      96                 // B*C per image
#define NBINS     64
#define BPR       8                  // blocks per row
#define CHUNK     (HW / BPR)         // 32768 elements per block
#define THREADS   256
#define F4_ITERS  (CHUNK / 4 / THREADS)  // 32 float4 per thread -> 128 elems
#define NBLOCKS   (2 * ROWS * BPR)   // 1536 (6 blocks/CU)
#define RING      8                  // float4 loads in flight per wave

typedef unsigned long long u64;

// 4:2 carry-save compress four one-hot u64s into 8 bit-planes p0..p7.
// bit bb of pk = bit k of this thread's count for bin bb. Max count 128.
#define PROC4(v) do {                                                   \
    int b0 = min((int)((v).x * 64.0f), 63);                             \
    int b1 = min((int)((v).y * 64.0f), 63);                             \
    int b2 = min((int)((v).z * 64.0f), 63);                             \
    int b3 = min((int)((v).w * 64.0f), 63);                             \
    u64 m0 = 1ull << b0, m1 = 1ull << b1;                               \
    u64 m2 = 1ull << b2, m3 = 1ull << b3;                               \
    u64 s1 = m0 ^ m1, c1 = m0 & m1;                                     \
    u64 s2 = m2 ^ m3, c2 = m2 & m3;                                     \
    u64 S  = s1 ^ s2, C  = s1 & s2;                                     \
    u64 g0 = p0 & S;  p0 ^= S;                                          \
    u64 u  = c1 ^ c2, vv = c1 & c2;                                     \
    u64 s3 = u ^ C,   w  = u & C;                                       \
    u64 t3 = vv | w;                                                    \
    u64 t  = s3 ^ g0;                                                   \
    u64 g1 = (p1 & t) | (s3 & g0);  p1 ^= t;                            \
    u64 t2 = t3 ^ g1;                                                   \
    u64 g2 = (p2 & t2) | (t3 & g1); p2 ^= t2;                           \
    u64 g3 = p3 & g2; p3 ^= g2;                                         \
    u64 g4 = p4 & g3; p4 ^= g3;                                         \
    u64 g5 = p5 & g4; p5 ^= g4;                                         \
    u64 g6 = p6 & g5; p6 ^= g5;                                         \
    p7 ^= g6;                                                           \
} while (0)

// One pipeline stage: consume fk, then immediately re-issue its load.
// sched_barrier(0) pins the reload before the next stage's compute.
#define STAGE(fk, idx) do {                                             \
    float4 cur = fk;                                                    \
    fk = q[(idx) * THREADS];                                            \
    PROC4(cur);                                                         \
    __builtin_amdgcn_sched_barrier(0);                                  \
} while (0)

__global__ __launch_bounds__(THREADS, 6)
void hist_kernel(const float* __restrict__ fake,
                 const float* __restrict__ real,
                 unsigned int* __restrict__ partial) {
    __shared__ unsigned int bhist[NBINS];

    const int tid  = threadIdx.x;
    const int lane = tid & 63;

    if (tid < NBINS) bhist[tid] = 0u;
    __syncthreads();

    const int b     = blockIdx.x;          // 0 .. 1535
    const int chunk = b & (BPR - 1);
    const int rowg  = b >> 3;              // 0..191: img*ROWS + row
    const float* src = (rowg < ROWS) ? fake : real;
    const int row    = (rowg < ROWS) ? rowg : (rowg - ROWS);

    const float4* __restrict__ q =
        (const float4*)(src + (size_t)row * HW + (size_t)chunk * CHUNK) + tid;

    u64 p0 = 0, p1 = 0, p2 = 0, p3 = 0, p4 = 0, p5 = 0, p6 = 0, p7 = 0;

    // Prologue: fill the ring — 8 wave-loads (8KB) in flight.
    float4 f0 = q[0 * THREADS];
    float4 f1 = q[1 * THREADS];
    float4 f2 = q[2 * THREADS];
    float4 f3 = q[3 * THREADS];
    float4 f4 = q[4 * THREADS];
    float4 f5 = q[5 * THREADS];
    float4 f6 = q[6 * THREADS];
    float4 f7 = q[7 * THREADS];
    __builtin_amdgcn_sched_barrier(0);

    // Steady state: every stage consumes one slot and refills it.
#pragma unroll 1
    for (int i = RING; i <= F4_ITERS - RING; i += RING) {
        STAGE(f0, i + 0);
        STAGE(f1, i + 1);
        STAGE(f2, i + 2);
        STAGE(f3, i + 3);
        STAGE(f4, i + 4);
        STAGE(f5, i + 5);
        STAGE(f6, i + 6);
        STAGE(f7, i + 7);
    }
    // Epilogue: drain the ring.
    PROC4(f0); PROC4(f1); PROC4(f2); PROC4(f3);
    PROC4(f4); PROC4(f5); PROC4(f6); PROC4(f7);

    // Flush: wave-sum per bin via ballot+popcount of each plane's bit.
    unsigned mycnt = 0;
#pragma unroll
    for (int bb = 0; bb < NBINS; ++bb) {
        unsigned ws =
              (unsigned)__popcll(__ballot((unsigned)((p0 >> bb) & 1ull)))
            + ((unsigned)__popcll(__ballot((unsigned)((p1 >> bb) & 1ull))) << 1)
            + ((unsigned)__popcll(__ballot((unsigned)((p2 >> bb) & 1ull))) << 2)
            + ((unsigned)__popcll(__ballot((unsigned)((p3 >> bb) & 1ull))) << 3)
            + ((unsigned)__popcll(__ballot((unsigned)((p4 >> bb) & 1ull))) << 4)
            + ((unsigned)__popcll(__ballot((unsigned)((p5 >> bb) & 1ull))) << 5)
            + ((unsigned)__popcll(__ballot((unsigned)((p6 >> bb) & 1ull))) << 6)
            + ((unsigned)__popcll(__ballot((unsigned)((p7 >> bb) & 1ull))) << 7);
        if (lane == bb) mycnt = ws;
    }
    // One LDS atomic per lane per wave for the entire kernel.
    atomicAdd(&bhist[lane], mycnt);
    __syncthreads();

    if (tid < NBINS)
        partial[(size_t)b * NBINS + tid] = bhist[tid];   // plain store
}

// Stage 1: 24 blocks x 256 threads; each thread owns one (row,bin) pair.
__global__ __launch_bounds__(256)
void loss1_kernel(const unsigned int* __restrict__ partial,
                  unsigned int* __restrict__ blocksum) {
    const int tid = threadIdx.x;
    const int g   = blockIdx.x * 256 + tid;   // 0..6143
    const int r   = g >> 6;
    const int bb  = g & 63;
    unsigned cf = 0, cr = 0;
#pragma unroll
    for (int c = 0; c < BPR; ++c) {
        cf += partial[((r * BPR + c) * NBINS) + bb];
        cr += partial[(((ROWS + r) * BPR + c) * NBINS) + bb];
    }
    int d = (int)cf - (int)cr;
    int a = (d < 0) ? -d : d;
#pragma unroll
    for (int off = 32; off > 0; off >>= 1)
        a += __shfl_down(a, off, 64);
    __shared__ int wsum[4];
    if ((tid & 63) == 0) wsum[tid >> 6] = a;
    __syncthreads();
    if (tid == 0)
        blocksum[blockIdx.x] = (unsigned)(wsum[0] + wsum[1] + wsum[2] + wsum[3]);
}

// Stage 2: one wave folds the 24 block sums.
__global__ __launch_bounds__(64)
void loss2_kernel(const unsigned int* __restrict__ blocksum,
                  float* __restrict__ out) {
    const int lane = threadIdx.x;
    int a = (lane < 24) ? (int)blocksum[lane] : 0;
#pragma unroll
    for (int off = 32; off > 0; off >>= 1)
        a += __shfl_down(a, off, 64);
    if (lane == 0)
        out[0] = (float)((double)a / (262144.0 * 6144.0));
}

extern "C" void kernel_launch(void* const* d_in, const int* in_sizes, int n_in,
                              void* d_out, int out_size, void* d_ws, size_t ws_size,
                              hipStream_t stream) {
    const float* fake = (const float*)d_in[0];
    const float* real = (const float*)d_in[1];
    unsigned int* partial  = (unsigned int*)d_ws;            // 1536*64 u32 = 393216 B
    unsigned int* blocksum = partial + NBLOCKS * NBINS;      // 24 u32
    float* out = (float*)d_out;

    hist_kernel<<<NBLOCKS, THREADS, 0, stream>>>(fake, real, partial);
    loss1_kernel<<<24, 256, 0, stream>>>(partial, blocksum);
    loss2_kernel<<<1, 64, 0, stream>>>(blocksum, out);
}

// Round 4
// 226.711 us; speedup vs baseline: 1.1119x; 1.1119x over previous
//
#include <hip/hip_runtime.h>

// HistogramLoss: two [32,3,512,512] fp32 inputs, per-(B,C) 64-bin histogram
// over [0,1], row-normalized (row count exactly 2^18), L1 mean of diff.
//
// R9: R8 proved the Little's-law theory (cold fetch rate 1.17->2.5 TB/s)
// but spilled the ring: __launch_bounds__(256,6) caps VGPR at ~80, and
// ring(32)+planes(16)+CSA temps(~25)+addr(~8) is just over -> allocator
// spilled ring slots to scratch (WRITE_SIZE 0.4->128MB, FETCH +48MB,
// VGPR_Count=40), hist 86->112us. Fixes, keeping the R8 structure:
//  (1) __launch_bounds__(256,4): VGPR cap 128, ~85 used, no spill.
//      4 blocks/CU x 4 waves x 8KB ring = 128KB in flight per CU.
//  (2) sched_barrier(0x7) (ALU may cross, VMEM pinned): keeps load-issue
//      discipline, frees VALU scheduling -> shorter live ranges.
//  (3) STAGE consumes fk then reloads it (no cur copy): -4 regs, -4 movs;
//      reload still ~600 instrs ahead of its next use.
// 8 planes, 128 elems/thread, capacity 255 -> exact integer counting.

#define HW        262144             // 512*512 = 2^18
#define ROWS      96                 // B*C per image
#define NBINS     64
#define BPR       8                  // blocks per row
#define CHUNK     (HW / BPR)         // 32768 elements per block
#define THREADS   256
#define F4_ITERS  (CHUNK / 4 / THREADS)  // 32 float4 per thread -> 128 elems
#define NBLOCKS   (2 * ROWS * BPR)   // 1536
#define RING      8                  // float4 loads in flight per wave

typedef unsigned long long u64;

// 4:2 carry-save compress four one-hot u64s into 8 bit-planes p0..p7.
// bit bb of pk = bit k of this thread's count for bin bb. Max count 128.
#define PROC4(v) do {                                                   \
    int b0 = min((int)((v).x * 64.0f), 63);                             \
    int b1 = min((int)((v).y * 64.0f), 63);                             \
    int b2 = min((int)((v).z * 64.0f), 63);                             \
    int b3 = min((int)((v).w * 64.0f), 63);                             \
    u64 m0 = 1ull << b0, m1 = 1ull << b1;                               \
    u64 m2 = 1ull << b2, m3 = 1ull << b3;                               \
    u64 s1 = m0 ^ m1, c1 = m0 & m1;                                     \
    u64 s2 = m2 ^ m3, c2 = m2 & m3;                                     \
    u64 S  = s1 ^ s2, C  = s1 & s2;                                     \
    u64 g0 = p0 & S;  p0 ^= S;                                          \
    u64 u  = c1 ^ c2, vv = c1 & c2;                                     \
    u64 s3 = u ^ C,   w  = u & C;                                       \
    u64 t3 = vv | w;                                                    \
    u64 t  = s3 ^ g0;                                                   \
    u64 g1 = (p1 & t) | (s3 & g0);  p1 ^= t;                            \
    u64 t2 = t3 ^ g1;                                                   \
    u64 g2 = (p2 & t2) | (t3 & g1); p2 ^= t2;                           \
    u64 g3 = p3 & g2; p3 ^= g2;                                         \
    u64 g4 = p4 & g3; p4 ^= g3;                                         \
    u64 g5 = p5 & g4; p5 ^= g4;                                         \
    u64 g6 = p6 & g5; p6 ^= g5;                                         \
    p7 ^= g6;                                                           \
} while (0)

// One pipeline stage: consume slot fk, then immediately re-issue its load.
// sched_barrier(0x7): ALU/VALU/SALU may cross (scheduler freedom), VMEM
// may NOT -> the reload cannot sink past the next stage's compute.
#define STAGE(fk, idx) do {                                             \
    PROC4(fk);                                                          \
    fk = q[(idx) * THREADS];                                            \
    __builtin_amdgcn_sched_barrier(0x7);                                \
} while (0)

__global__ __launch_bounds__(THREADS, 4)
void hist_kernel(const float* __restrict__ fake,
                 const float* __restrict__ real,
                 unsigned int* __restrict__ partial) {
    __shared__ unsigned int bhist[NBINS];

    const int tid  = threadIdx.x;
    const int lane = tid & 63;

    if (tid < NBINS) bhist[tid] = 0u;
    __syncthreads();

    const int b     = blockIdx.x;          // 0 .. 1535
    const int chunk = b & (BPR - 1);
    const int rowg  = b >> 3;              // 0..191: img*ROWS + row
    const float* src = (rowg < ROWS) ? fake : real;
    const int row    = (rowg < ROWS) ? rowg : (rowg - ROWS);

    const float4* __restrict__ q =
        (const float4*)(src + (size_t)row * HW + (size_t)chunk * CHUNK) + tid;

    u64 p0 = 0, p1 = 0, p2 = 0, p3 = 0, p4 = 0, p5 = 0, p6 = 0, p7 = 0;

    // Prologue: fill the ring — 8 wave-loads (8KB/wave) in flight.
    float4 f0 = q[0 * THREADS];
    float4 f1 = q[1 * THREADS];
    float4 f2 = q[2 * THREADS];
    float4 f3 = q[3 * THREADS];
    float4 f4 = q[4 * THREADS];
    float4 f5 = q[5 * THREADS];
    float4 f6 = q[6 * THREADS];
    float4 f7 = q[7 * THREADS];
    __builtin_amdgcn_sched_barrier(0x7);

    // Steady state: every stage consumes one slot and refills it.
#pragma unroll 1
    for (int i = RING; i <= F4_ITERS - RING; i += RING) {
        STAGE(f0, i + 0);
        STAGE(f1, i + 1);
        STAGE(f2, i + 2);
        STAGE(f3, i + 3);
        STAGE(f4, i + 4);
        STAGE(f5, i + 5);
        STAGE(f6, i + 6);
        STAGE(f7, i + 7);
    }
    // Epilogue: drain the ring.
    PROC4(f0); PROC4(f1); PROC4(f2); PROC4(f3);
    PROC4(f4); PROC4(f5); PROC4(f6); PROC4(f7);

    // Flush: wave-sum per bin via ballot+popcount of each plane's bit.
    unsigned mycnt = 0;
#pragma unroll
    for (int bb = 0; bb < NBINS; ++bb) {
        unsigned ws =
              (unsigned)__popcll(__ballot((unsigned)((p0 >> bb) & 1ull)))
            + ((unsigned)__popcll(__ballot((unsigned)((p1 >> bb) & 1ull))) << 1)
            + ((unsigned)__popcll(__ballot((unsigned)((p2 >> bb) & 1ull))) << 2)
            + ((unsigned)__popcll(__ballot((unsigned)((p3 >> bb) & 1ull))) << 3)
            + ((unsigned)__popcll(__ballot((unsigned)((p4 >> bb) & 1ull))) << 4)
            + ((unsigned)__popcll(__ballot((unsigned)((p5 >> bb) & 1ull))) << 5)
            + ((unsigned)__popcll(__ballot((unsigned)((p6 >> bb) & 1ull))) << 6)
            + ((unsigned)__popcll(__ballot((unsigned)((p7 >> bb) & 1ull))) << 7);
        if (lane == bb) mycnt = ws;
    }
    // One LDS atomic per lane per wave for the entire kernel.
    atomicAdd(&bhist[lane], mycnt);
    __syncthreads();

    if (tid < NBINS)
        partial[(size_t)b * NBINS + tid] = bhist[tid];   // plain store
}

// Stage 1: 24 blocks x 256 threads; each thread owns one (row,bin) pair.
__global__ __launch_bounds__(256)
void loss1_kernel(const unsigned int* __restrict__ partial,
                  unsigned int* __restrict__ blocksum) {
    const int tid = threadIdx.x;
    const int g   = blockIdx.x * 256 + tid;   // 0..6143
    const int r   = g >> 6;
    const int bb  = g & 63;
    unsigned cf = 0, cr = 0;
#pragma unroll
    for (int c = 0; c < BPR; ++c) {
        cf += partial[((r * BPR + c) * NBINS) + bb];
        cr += partial[(((ROWS + r) * BPR + c) * NBINS) + bb];
    }
    int d = (int)cf - (int)cr;
    int a = (d < 0) ? -d : d;
#pragma unroll
    for (int off = 32; off > 0; off >>= 1)
        a += __shfl_down(a, off, 64);
    __shared__ int wsum[4];
    if ((tid & 63) == 0) wsum[tid >> 6] = a;
    __syncthreads();
    if (tid == 0)
        blocksum[blockIdx.x] = (unsigned)(wsum[0] + wsum[1] + wsum[2] + wsum[3]);
}

// Stage 2: one wave folds the 24 block sums.
__global__ __launch_bounds__(64)
void loss2_kernel(const unsigned int* __restrict__ blocksum,
                  float* __restrict__ out) {
    const int lane = threadIdx.x;
    int a = (lane < 24) ? (int)blocksum[lane] : 0;
#pragma unroll
    for (int off = 32; off > 0; off >>= 1)
        a += __shfl_down(a, off, 64);
    if (lane == 0)
        out[0] = (float)((double)a / (262144.0 * 6144.0));
}

extern "C" void kernel_launch(void* const* d_in, const int* in_sizes, int n_in,
                              void* d_out, int out_size, void* d_ws, size_t ws_size,
                              hipStream_t stream) {
    const float* fake = (const float*)d_in[0];
    const float* real = (const float*)d_in[1];
    unsigned int* partial  = (unsigned int*)d_ws;            // 1536*64 u32 = 393216 B
    unsigned int* blocksum = partial + NBLOCKS * NBINS;      // 24 u32
    float* out = (float*)d_out;

    hist_kernel<<<NBLOCKS, THREADS, 0, stream>>>(fake, real, partial);
    loss1_kernel<<<24, 256, 0, stream>>>(partial, blocksum);
    loss2_kernel<<<1, 64, 0, stream>>>(blocksum, out);
}

// Round 5
// 224.532 us; speedup vs baseline: 1.1227x; 1.0097x over previous
//
#include <hip/hip_runtime.h>

// HistogramLoss: two [32,3,512,512] fp32 inputs, per-(B,C) 64-bin histogram
// over [0,1], row-normalized (row count exactly 2^18), L1 mean of diff.
//
// R10: DMA staging with explicit counted waits. History: R5 (LDS atomics),
// R7 (named-reg pipeline), R9 (8-deep reg ring, no spill, VMEM order
// pinned) ALL land at 86us / 1.17 TB/s / VALUBusy 38% -> VGPR-destination
// loads never get >~1 request in flight per wave (compiler waitcnt
// degenerates to per-stage full waits); R8's scratch traffic proved the
// memory system delivers 2.5+ TB/s given independent requests. So: switch
// to __builtin_amdgcn_global_load_lds (fire-and-forget DMA, no dest reg,
// nothing for the scheduler to mangle) + inline-asm s_waitcnt vmcnt(N)
// counted by hand (guide T3/T4). Ring of 4 x 2KB LDS tiles per wave:
// issue tile t+3, wait vmcnt(6), consume tile t -> 8 x 1KB wave-loads in
// flight per wave BY CONSTRUCTION. Per-wave private buffers -> zero
// __syncthreads in the loop. LDS exactly 32KB/block (bhist aliased onto
// dead staging) -> 5 blocks/CU = 20 waves/CU = 120-160KB in flight/CU.
// Histogram is permutation-invariant: each lane reads back its own float4
// (identity mapping, conflict-free ds_read_b128). 8 planes, 128
// elems/thread, capacity 255 -> exact integer counting (absmax 0).
// If THIS still runs 86us, ~1.2 TB/s is a real ceiling for this shape.

#define HW        262144             // 512*512 = 2^18
#define ROWS      96                 // B*C per image
#define NBINS     64
#define BPR       8                  // blocks per row
#define CHUNK     (HW / BPR)         // 32768 elements per block (128KB)
#define THREADS   256
#define NBLOCKS   (2 * ROWS * BPR)   // 1536

#define WAVE_ELEMS 8192              // f32 per wave (32KB)
#define TILE_ELEMS 512               // f32 per tile (2KB)
#define NTILES     16                // tiles per wave
#define RBUF       4                 // ring buffers per wave

typedef unsigned long long u64;
typedef unsigned int u32;
typedef const __attribute__((address_space(1))) u32* gas_t;  // global
typedef __attribute__((address_space(3))) u32* las_t;        // LDS

// 4:2 carry-save compress four one-hot u64s into 8 bit-planes p0..p7.
// bit bb of pk = bit k of this thread's count for bin bb. Max count 128.
#define PROC4(v) do {                                                   \
    int b0 = min((int)((v).x * 64.0f), 63);                             \
    int b1 = min((int)((v).y * 64.0f), 63);                             \
    int b2 = min((int)((v).z * 64.0f), 63);                             \
    int b3 = min((int)((v).w * 64.0f), 63);                             \
    u64 m0 = 1ull << b0, m1 = 1ull << b1;                               \
    u64 m2 = 1ull << b2, m3 = 1ull << b3;                               \
    u64 s1 = m0 ^ m1, c1 = m0 & m1;                                     \
    u64 s2 = m2 ^ m3, c2 = m2 & m3;                                     \
    u64 S  = s1 ^ s2, C  = s1 & s2;                                     \
    u64 g0 = p0 & S;  p0 ^= S;                                          \
    u64 u  = c1 ^ c2, vv = c1 & c2;                                     \
    u64 s3 = u ^ C,   w  = u & C;                                       \
    u64 t3 = vv | w;                                                    \
    u64 t  = s3 ^ g0;                                                   \
    u64 g1 = (p1 & t) | (s3 & g0);  p1 ^= t;                            \
    u64 t2 = t3 ^ g1;                                                   \
    u64 g2 = (p2 & t2) | (t3 & g1); p2 ^= t2;                           \
    u64 g3 = p3 & g2; p3 ^= g2;                                         \
    u64 g4 = p4 & g3; p4 ^= g3;                                         \
    u64 g5 = p5 & g4; p5 ^= g4;                                         \
    u64 g6 = p6 & g5; p6 ^= g5;                                         \
    p7 ^= g6;                                                           \
} while (0)

// Issue tile t: two 1KB DMA wave-loads into ring slot (t&3).
// LDS dest is wave-uniform base (+ HW adds lane*16); global src is
// per-lane -> identity mapping lane l <- elems [4l..4l+3] of each KB.
#define ISSUE(t) do {                                                   \
    float* lp = lbase + ((t) & (RBUF - 1)) * TILE_ELEMS;                \
    const float* gp = gbase + (t) * TILE_ELEMS + lane * 4;              \
    __builtin_amdgcn_global_load_lds((gas_t)gp,        (las_t)(void*)lp,        16, 0, 0); \
    __builtin_amdgcn_global_load_lds((gas_t)(gp + 256),(las_t)(void*)(lp + 256),16, 0, 0); \
} while (0)

// Consume tile t: each lane reads back its own two float4s.
#define CONSUME(t) do {                                                 \
    const float4* rp =                                                  \
        (const float4*)(lbase + ((t) & (RBUF - 1)) * TILE_ELEMS);       \
    float4 v0 = rp[lane];                                               \
    float4 v1 = rp[lane + 64];                                          \
    PROC4(v0); PROC4(v1);                                               \
} while (0)

__global__ __launch_bounds__(THREADS, 5)
void hist_kernel(const float* __restrict__ fake,
                 const float* __restrict__ real,
                 unsigned int* __restrict__ partial) {
    // 4 waves x 4 ring bufs x 512 f32 = 32KB exactly (5 blocks/CU).
    __shared__ __align__(16) float lds[4 * RBUF * TILE_ELEMS];

    const int tid  = threadIdx.x;
    const int lane = tid & 63;
    const int wv   = tid >> 6;

    const int b     = blockIdx.x;          // 0 .. 1535
    const int chunk = b & (BPR - 1);
    const int rowg  = b >> 3;              // 0..191: img*ROWS + row
    const float* src = (rowg < ROWS) ? fake : real;
    const int row    = (rowg < ROWS) ? rowg : (rowg - ROWS);

    const float* gbase = src + (size_t)row * HW + (size_t)chunk * CHUNK
                             + wv * WAVE_ELEMS;
    float* lbase = &lds[wv * RBUF * TILE_ELEMS];

    u64 p0 = 0, p1 = 0, p2 = 0, p3 = 0, p4 = 0, p5 = 0, p6 = 0, p7 = 0;

    // Prologue: 3 tiles (6 KB) in flight before first consume.
    ISSUE(0); ISSUE(1); ISSUE(2);

    // Steady state: issue t+3, wait tile t's 2 loads (6 newer allowed),
    // consume t. No __syncthreads — each wave syncs only its own vmcnt.
#pragma unroll 1
    for (int t = 0; t < NTILES - 3; ++t) {   // t = 0..12
        __builtin_amdgcn_sched_barrier(0);   // pin: prev consume's ds_reads
                                             // stay before this DMA reuse
        ISSUE(t + 3);
        asm volatile("s_waitcnt vmcnt(6)" ::: "memory");
        CONSUME(t);
    }
    // Drain.
    asm volatile("s_waitcnt vmcnt(4)" ::: "memory");
    CONSUME(13);
    asm volatile("s_waitcnt vmcnt(2)" ::: "memory");
    CONSUME(14);
    asm volatile("s_waitcnt vmcnt(0)" ::: "memory");
    CONSUME(15);

    // Flush: wave-sum per bin via ballot+popcount of each plane's bit.
    unsigned mycnt = 0;
#pragma unroll
    for (int bb = 0; bb < NBINS; ++bb) {
        unsigned ws =
              (unsigned)__popcll(__ballot((unsigned)((p0 >> bb) & 1ull)))
            + ((unsigned)__popcll(__ballot((unsigned)((p1 >> bb) & 1ull))) << 1)
            + ((unsigned)__popcll(__ballot((unsigned)((p2 >> bb) & 1ull))) << 2)
            + ((unsigned)__popcll(__ballot((unsigned)((p3 >> bb) & 1ull))) << 3)
            + ((unsigned)__popcll(__ballot((unsigned)((p4 >> bb) & 1ull))) << 4)
            + ((unsigned)__popcll(__ballot((unsigned)((p5 >> bb) & 1ull))) << 5)
            + ((unsigned)__popcll(__ballot((unsigned)((p6 >> bb) & 1ull))) << 6)
            + ((unsigned)__popcll(__ballot((unsigned)((p7 >> bb) & 1ull))) << 7);
        if (lane == bb) mycnt = ws;
    }

    // Staging LDS is dead now — alias the block histogram onto it.
    unsigned int* bhist = (unsigned int*)lds;
    __syncthreads();                       // all waves done with staging
    if (tid < NBINS) bhist[tid] = 0u;
    __syncthreads();
    atomicAdd(&bhist[lane], mycnt);        // one ds_add per lane per wave
    __syncthreads();
    if (tid < NBINS)
        partial[(size_t)b * NBINS + tid] = bhist[tid];   // plain store
}

// Stage 1: 24 blocks x 256 threads; each thread owns one (row,bin) pair.
__global__ __launch_bounds__(256)
void loss1_kernel(const unsigned int* __restrict__ partial,
                  unsigned int* __restrict__ blocksum) {
    const int tid = threadIdx.x;
    const int g   = blockIdx.x * 256 + tid;   // 0..6143
    const int r   = g >> 6;
    const int bb  = g & 63;
    unsigned cf = 0, cr = 0;
#pragma unroll
    for (int c = 0; c < BPR; ++c) {
        cf += partial[((r * BPR + c) * NBINS) + bb];
        cr += partial[(((ROWS + r) * BPR + c) * NBINS) + bb];
    }
    int d = (int)cf - (int)cr;
    int a = (d < 0) ? -d : d;
#pragma unroll
    for (int off = 32; off > 0; off >>= 1)
        a += __shfl_down(a, off, 64);
    __shared__ int wsum[4];
    if ((tid & 63) == 0) wsum[tid >> 6] = a;
    __syncthreads();
    if (tid == 0)
        blocksum[blockIdx.x] = (unsigned)(wsum[0] + wsum[1] + wsum[2] + wsum[3]);
}

// Stage 2: one wave folds the 24 block sums.
__global__ __launch_bounds__(64)
void loss2_kernel(const unsigned int* __restrict__ blocksum,
                  float* __restrict__ out) {
    const int lane = threadIdx.x;
    int a = (lane < 24) ? (int)blocksum[lane] : 0;
#pragma unroll
    for (int off = 32; off > 0; off >>= 1)
        a += __shfl_down(a, off, 64);
    if (lane == 0)
        out[0] = (float)((double)a / (262144.0 * 6144.0));
}

extern "C" void kernel_launch(void* const* d_in, const int* in_sizes, int n_in,
                              void* d_out, int out_size, void* d_ws, size_t ws_size,
                              hipStream_t stream) {
    const float* fake = (const float*)d_in[0];
    const float* real = (const float*)d_in[1];
    unsigned int* partial  = (unsigned int*)d_ws;            // 1536*64 u32 = 393216 B
    unsigned int* blocksum = partial + NBLOCKS * NBINS;      // 24 u32
    float* out = (float*)d_out;

    hist_kernel<<<NBLOCKS, THREADS, 0, stream>>>(fake, real, partial);
    loss1_kernel<<<24, 256, 0, stream>>>(partial, blocksum);
    loss2_kernel<<<1, 64, 0, stream>>>(blocksum, out);
}